// Round 2
// baseline (956.104 us; speedup 1.0000x reference)
//
#include <hip/hip_runtime.h>
#include <hip/hip_bf16.h>

// Problem constants
#define NN      2048
#define NODES   64
#define DIN     4
#define DOUT    4
#define MM      128
#define DEG     8
#define PP      32
#define JITTER  1e-4f

typedef __attribute__((ext_vector_type(8))) short short8;
typedef __attribute__((ext_vector_type(4))) float f32x4;

__device__ __forceinline__ unsigned short f2b(float f) {
    union { float f; unsigned int u; } v; v.f = f;
    unsigned int u = v.u;
    u += 0x7fffu + ((u >> 16) & 1u);
    return (unsigned short)(u >> 16);
}
__device__ __forceinline__ float b2f(unsigned short h) {
    union { unsigned int u; float f; } v; v.u = ((unsigned int)h) << 16;
    return v.f;
}

// ---------------- K0: transpose X (2048x256) -> XT (256x2048) ----------------
__global__ __launch_bounds__(256) void k_transpose(const float* __restrict__ X,
                                                   float* __restrict__ XT) {
    int n = blockIdx.x, c = threadIdx.x;
    XT[c * NN + n] = X[n * 256 + c];
}

// ---------------- K1: per-node Ku = rbf(Zn,Zn) + jitter*I ----------------
__global__ __launch_bounds__(256) void k_ku(const float* __restrict__ Z,
                                            const int* __restrict__ pa,
                                            float* __restrict__ Kub) {
    __shared__ float Zs[128][33];
    __shared__ float zsq[128];
    __shared__ int cols[32];
    int node = blockIdx.x, t = threadIdx.x;
    if (t < 32) cols[t] = pa[node * 32 + t];
    __syncthreads();
    for (int i = t; i < 128 * 32; i += 256) {
        int m = i >> 5, j = i & 31;
        Zs[m][j] = Z[m * 256 + cols[j]];
    }
    __syncthreads();
    if (t < 128) {
        float s = 0.f;
        for (int j = 0; j < 32; j++) { float v = Zs[t][j]; s += v * v; }
        zsq[t] = s;
    }
    __syncthreads();
    int j = t & 127, ih = t >> 7;
    for (int ii = 0; ii < 64; ii++) {
        int i = ih * 64 + ii;
        float d = 0.f;
        #pragma unroll
        for (int p = 0; p < 32; p++) d += Zs[i][p] * Zs[j][p];
        float sq = zsq[i] + zsq[j] - 2.f * d;
        sq = fmaxf(sq, 0.f);
        float v = __expf(-0.5f * sq);
        if (i == j) v += JITTER;
        Kub[node * 16384 + i * 128 + j] = v;
    }
}

// ---------------- K2: register-resident Gauss-Jordan inverse (no pivot) ------
// Each thread owns half a row (64 floats in VGPRs). Pivot row broadcast via
// double-buffered LDS; A[r][k] exchanged between the two half-row threads via
// shfl_xor(,1). One barrier per step.
__global__ __launch_bounds__(256) void k_inv(const float* __restrict__ Kub,
                                             float* __restrict__ Kinvf,
                                             unsigned short* __restrict__ Hbuf) {
    __shared__ float prow[2][128];
    int node = blockIdx.x, t = threadIdx.x;
    int r = t >> 1, h = t & 1;           // row, column-half (h*64 .. h*64+63)
    float a[64];
    const float* src = Kub + (size_t)node * 16384 + r * 128 + h * 64;
    #pragma unroll
    for (int j = 0; j < 64; j += 4) {
        f32x4 v = *(const f32x4*)(src + j);
        a[j] = v.x; a[j + 1] = v.y; a[j + 2] = v.z; a[j + 3] = v.w;
    }
    #pragma unroll 1
    for (int k = 0; k < 128; ++k) {
        float* pb = prow[k & 1];
        if (r == k) {
            #pragma unroll
            for (int j = 0; j < 64; ++j) pb[h * 64 + j] = a[j];
        }
        __syncthreads();
        float ip = 1.0f / pb[k];
        int kh = k >> 6, kl = k & 63;
        float cim = (kh == h) ? a[kl] : 0.f;
        float ci = cim + __shfl_xor(cim, 1);
        if (r != k) {
            float f = -ci * ip;
            const float* pbh = pb + h * 64;
            #pragma unroll
            for (int j = 0; j < 64; ++j) a[j] = fmaf(f, pbh[j], a[j]);
            if (kh == h) a[kl] = f;
        } else {
            #pragma unroll
            for (int j = 0; j < 64; ++j) a[j] *= ip;
            if (kh == h) a[kl] = ip;
        }
        // double-buffered prow: next step writes the other buffer, and the
        // step-k buffer is only rewritten after two more barriers -> safe.
    }
    float* dstf = Kinvf + (size_t)node * 16384 + r * 128 + h * 64;
    unsigned short* dstb = Hbuf + (size_t)node * 81920 + (512 + r) * 128 + h * 64;
    #pragma unroll
    for (int j = 0; j < 64; j += 4) {
        f32x4 v; v.x = a[j]; v.y = a[j + 1]; v.z = a[j + 2]; v.w = a[j + 3];
        *(f32x4*)(dstf + j) = v;
        dstb[j] = f2b(a[j]); dstb[j + 1] = f2b(a[j + 1]);
        dstb[j + 2] = f2b(a[j + 2]); dstb[j + 3] = f2b(a[j + 3]);
    }
}

// ---------------- K3: W[d] = Kinv @ qmu_d ----------------
__global__ __launch_bounds__(256) void k_w(const float* __restrict__ Kinvf,
                                           const float* __restrict__ qmu,
                                           float* __restrict__ Wg) {
    int node = blockIdx.x, t = threadIdx.x;
    __shared__ float qs[512];  // [m][d]
    for (int i = t; i < 512; i += 256) qs[i] = qmu[(i >> 2) * 256 + node * 4 + (i & 3)];
    __syncthreads();
    for (int p = 0; p < 2; p++) {
        int o = t + p * 256;
        int d = o >> 7, i = o & 127;
        float s = 0.f;
        for (int j = 0; j < 128; j++)
            s += Kinvf[node * 16384 + i * 128 + j] * qs[j * 4 + d];
        Wg[node * 512 + d * 128 + i] = s;
    }
}

// ---------------- K4: Gt[d][m][j] = sum_p Lq[p][m] * Kinv[p][j]  (p>=m) ------
__global__ __launch_bounds__(256) void k_gt(const float* __restrict__ Kinvf,
                                            const float* __restrict__ qsqrt,
                                            unsigned short* __restrict__ Hbuf) {
    int nd = blockIdx.x;
    int node = nd >> 2, d = nd & 3;
    __shared__ float Lqs[32][132];
    __shared__ float Ks[32][132];
    int t = threadIdx.x;
    int tm = t & 15, tj = t >> 4;
    float acc[8][8] = {};
    const float* Lq = qsqrt + (size_t)nd * 16384;
    const float* Ki = Kinvf + (size_t)node * 16384;
    for (int pc = 0; pc < 128; pc += 32) {
        __syncthreads();
        for (int idx = t; idx < 32 * 128; idx += 256) {
            int pp = idx >> 7, m = idx & 127;
            int p = pc + pp;
            Lqs[pp][m] = (p >= m) ? Lq[p * 128 + m] : 0.f;
            Ks[pp][m] = Ki[p * 128 + m];
        }
        __syncthreads();
        for (int pp = 0; pp < 32; pp++) {
            float lv[8], kv[8];
            #pragma unroll
            for (int a = 0; a < 8; a++) lv[a] = Lqs[pp][tm * 8 + a];
            #pragma unroll
            for (int b = 0; b < 8; b++) kv[b] = Ks[pp][tj * 8 + b];
            #pragma unroll
            for (int a = 0; a < 8; a++)
                #pragma unroll
                for (int b = 0; b < 8; b++) acc[a][b] += lv[a] * kv[b];
        }
    }
    for (int a = 0; a < 8; a++)
        for (int b = 0; b < 8; b++)
            Hbuf[node * 81920 + (d * 128 + tm * 8 + a) * 128 + (tj * 8 + b)] = f2b(acc[a][b]);
}

// ---------------- K5: KufT[node][x][m] = rbf(Zn, Xn)  (bf16) ----------------
__global__ __launch_bounds__(256) void k_kuf(const float* __restrict__ Z,
                                             const float* __restrict__ XT,
                                             const int* __restrict__ pa,
                                             unsigned short* __restrict__ KufT) {
    int xt = blockIdx.x, node = blockIdx.y;
    __shared__ float Zs[128][33];
    __shared__ float Xs[32][132];
    __shared__ float zsq[128], xsq[128];
    __shared__ int cols[32];
    int t = threadIdx.x;
    if (t < 32) cols[t] = pa[node * 32 + t];
    __syncthreads();
    for (int i = t; i < 4096; i += 256) {
        int m = i >> 5, j = i & 31;
        Zs[m][j] = Z[m * 256 + cols[j]];
    }
    for (int i = t; i < 4096; i += 256) {
        int j = i >> 7, xl = i & 127;
        Xs[j][xl] = XT[cols[j] * NN + xt * 128 + xl];
    }
    __syncthreads();
    if (t < 128) {
        float s = 0.f;
        for (int j2 = 0; j2 < 32; j2++) { float v = Zs[t][j2]; s += v * v; }
        zsq[t] = s;
    } else {
        int x = t - 128;
        float s = 0.f;
        for (int j2 = 0; j2 < 32; j2++) { float v = Xs[j2][x]; s += v * v; }
        xsq[x] = s;
    }
    __syncthreads();
    int m = t & 127, xh = t >> 7;
    for (int xi = 0; xi < 64; xi++) {
        int xl = xh * 64 + xi;
        float dd = 0.f;
        #pragma unroll
        for (int p = 0; p < 32; p++) dd += Zs[m][p] * Xs[p][xl];
        float sq = zsq[m] + xsq[xl] - 2.f * dd;
        sq = fmaxf(sq, 0.f);
        KufT[(size_t)node * 262144 + (size_t)(xt * 128 + xl) * 128 + m] = f2b(__expf(-0.5f * sq));
    }
}

// ---------------- K6: main MFMA GEMM U = H @ Kuf + fused epilogue ------------
// grid (xt=16, rb=5, node=64), block 256 (4 waves, 2x2 wave tiling of 128x128)
__global__ __launch_bounds__(256) void k_main(const unsigned short* __restrict__ Hbuf,
                                              const unsigned short* __restrict__ KufT,
                                              const float* __restrict__ Wg,
                                              float* __restrict__ vsq,
                                              float* __restrict__ tb,
                                              float* __restrict__ meanb) {
    int xt = blockIdx.x, rb = blockIdx.y, node = blockIdx.z;
    __shared__ unsigned short S[32768];   // As = S[0..16384), Bs = S[16384..32768)
    unsigned short* As = S;
    unsigned short* Bs = S + 16384;
    int t = threadIdx.x;

    // stage A: H rows rb*128..+128 (seg-XOR swizzle within each 256B row)
    const unsigned short* Hg = Hbuf + (size_t)node * 81920 + (size_t)rb * 16384;
    #pragma unroll
    for (int i = 0; i < 8; i++) {
        int cid = t + i * 256;
        int r = cid >> 4, s = cid & 15;
        short8 v = *(const short8*)(Hg + r * 128 + s * 8);
        *(short8*)(As + r * 128 + ((s ^ (r & 7)) * 8)) = v;
    }
    // stage B: KufT rows xt*128..+128
    const unsigned short* Kg = KufT + (size_t)node * 262144 + (size_t)xt * 16384;
    #pragma unroll
    for (int i = 0; i < 8; i++) {
        int cid = t + i * 256;
        int r = cid >> 4, s = cid & 15;
        short8 v = *(const short8*)(Kg + r * 128 + s * 8);
        *(short8*)(Bs + r * 128 + ((s ^ (r & 7)) * 8)) = v;
    }
    __syncthreads();

    int wid = t >> 6, lane = t & 63;
    int wmI = wid & 1, wnI = wid >> 1;
    int wm = wmI * 64, wn = wnI * 64;
    int lr = lane & 15, lk = lane >> 4;

    f32x4 acc[4][4] = {};
    #pragma unroll
    for (int ks = 0; ks < 4; ks++) {
        int seg = ks * 4 + lk;
        short8 av[4], bv[4];
        #pragma unroll
        for (int mi = 0; mi < 4; mi++) {
            int r = wm + mi * 16 + lr;
            av[mi] = *(const short8*)(As + r * 128 + ((seg ^ (r & 7)) * 8));
        }
        #pragma unroll
        for (int ni = 0; ni < 4; ni++) {
            int x = wn + ni * 16 + lr;
            bv[ni] = *(const short8*)(Bs + x * 128 + ((seg ^ (x & 7)) * 8));
        }
        #pragma unroll
        for (int mi = 0; mi < 4; mi++)
            #pragma unroll
            for (int ni = 0; ni < 4; ni++)
                acc[mi][ni] = __builtin_amdgcn_mfma_f32_16x16x32_bf16(av[mi], bv[ni], acc[mi][ni], 0, 0, 0);
    }
    __syncthreads();

    float* dpart = (float*)S;   // overlays As (dead); Bs stays live
    if (rb < 4) {
        float sv[4];
        #pragma unroll
        for (int ni = 0; ni < 4; ni++) {
            float s = 0.f;
            #pragma unroll
            for (int mi = 0; mi < 4; mi++)
                #pragma unroll
                for (int j = 0; j < 4; j++) { float v = acc[mi][ni][j]; s += v * v; }
            s += __shfl_xor(s, 16);
            s += __shfl_xor(s, 32);
            sv[ni] = s;
        }
        if (lk == 0)
            #pragma unroll
            for (int ni = 0; ni < 4; ni++)
                dpart[wmI * 128 + wn + ni * 16 + lr] = sv[ni];
        __syncthreads();
        if (t < 128)
            vsq[node * 8192 + rb * 2048 + xt * 128 + t] = dpart[t] + dpart[128 + t];
    } else {
        // t-term: sum_i U[i][x] * k[i][x]
        float sv[4];
        #pragma unroll
        for (int ni = 0; ni < 4; ni++) {
            int x = wn + ni * 16 + lr;
            float s = 0.f;
            #pragma unroll
            for (int mi = 0; mi < 4; mi++)
                #pragma unroll
                for (int j = 0; j < 4; j++) {
                    int m = wm + mi * 16 + lk * 4 + j;
                    int seg = (m >> 3) ^ (x & 7);
                    float kv = b2f(Bs[x * 128 + seg * 8 + (m & 7)]);
                    s += acc[mi][ni][j] * kv;
                }
            s += __shfl_xor(s, 16);
            s += __shfl_xor(s, 32);
            sv[ni] = s;
        }
        if (lk == 0)
            #pragma unroll
            for (int ni = 0; ni < 4; ni++)
                dpart[wmI * 128 + wn + ni * 16 + lr] = sv[ni];
        __syncthreads();
        if (t < 128)
            tb[node * 2048 + xt * 128 + t] = dpart[t] + dpart[128 + t];
        // mean[d][x] = sum_m W[d][m] * k[m][x]
        for (int p = 0; p < 2; p++) {
            int o = t + p * 256;
            int d = o >> 7, xl = o & 127;
            float s = 0.f;
            for (int m2 = 0; m2 < 128; m2++) {
                int seg = (m2 >> 3) ^ (xl & 7);
                s += Wg[node * 512 + d * 128 + m2] * b2f(Bs[xl * 128 + seg * 8 + (m2 & 7)]);
            }
            meanb[node * 8192 + d * 2048 + xt * 128 + xl] = s;
        }
    }
}

// ---------------- K7: assemble outputs (LDS transpose for coalescing) --------
__global__ __launch_bounds__(256) void k_out(const float* __restrict__ meanb,
                                             const float* __restrict__ vsq,
                                             const float* __restrict__ tb,
                                             float* __restrict__ out) {
    __shared__ float mt[16][261];
    __shared__ float vt[16][261];
    int x0 = blockIdx.x * 16, t = threadIdx.x;
    int xl = t & 15, ch = t >> 4;
    for (int cc = 0; cc < 16; cc++) {
        int c = ch * 16 + cc;
        mt[xl][c] = meanb[c * 2048 + x0 + xl];
        vt[xl][c] = 1.0f + vsq[c * 2048 + x0 + xl] - tb[(c >> 2) * 2048 + x0 + xl];
    }
    __syncthreads();
    for (int xx = 0; xx < 16; xx++) {
        out[(x0 + xx) * 256 + t] = mt[xx][t];
        out[524288 + (x0 + xx) * 256 + t] = vt[xx][t];
    }
}

extern "C" void kernel_launch(void* const* d_in, const int* in_sizes, int n_in,
                              void* d_out, int out_size, void* d_ws, size_t ws_size,
                              hipStream_t stream) {
    const float* X = (const float*)d_in[0];
    const float* Z = (const float*)d_in[1];
    const float* qmu = (const float*)d_in[2];
    const float* qsqrt = (const float*)d_in[3];
    const int* pa = (const int*)d_in[4];
    float* out = (float*)d_out;

    char* ws = (char*)d_ws;
    size_t off = 0;
    float* XT = (float*)(ws + off);           off += 524288ull * 4;     // 2 MB
    float* Kub = (float*)(ws + off);          off += 1048576ull * 4;    // 4 MB
    float* Kinvf = (float*)(ws + off);        off += 1048576ull * 4;    // 4 MB
    float* Wg = (float*)(ws + off);           off += 32768ull * 4;      // 128 KB
    float* vsq = (float*)(ws + off);          off += 524288ull * 4;     // 2 MB
    float* tb = (float*)(ws + off);           off += 131072ull * 4;     // 512 KB
    float* meanb = (float*)(ws + off);        off += 524288ull * 4;     // 2 MB
    unsigned short* Hbuf = (unsigned short*)(ws + off);  off += 5242880ull * 2;   // 10 MB
    unsigned short* KufT = (unsigned short*)(ws + off);  off += 16777216ull * 2;  // 32 MB

    k_transpose<<<2048, 256, 0, stream>>>(X, XT);
    k_ku<<<64, 256, 0, stream>>>(Z, pa, Kub);
    k_inv<<<64, 256, 0, stream>>>(Kub, Kinvf, Hbuf);
    k_w<<<64, 256, 0, stream>>>(Kinvf, qmu, Wg);
    k_gt<<<256, 256, 0, stream>>>(Kinvf, qsqrt, Hbuf);
    k_kuf<<<dim3(16, 64), 256, 0, stream>>>(Z, XT, pa, KufT);
    k_main<<<dim3(16, 5, 64), 256, 0, stream>>>(Hbuf, KufT, Wg, vsq, tb, meanb);
    k_out<<<128, 256, 0, stream>>>(meanb, vsq, tb, out);
}

// Round 3
// 356.801 us; speedup vs baseline: 2.6797x; 2.6797x over previous
//
#include <hip/hip_runtime.h>
#include <hip/hip_bf16.h>

// Problem constants
#define NN      2048
#define NODES   64
#define DIN     4
#define DOUT    4
#define MM      128
#define DEG     8
#define PP      32
#define JITTER  1e-4f

typedef __attribute__((ext_vector_type(8))) short short8;
typedef __attribute__((ext_vector_type(4))) float f32x4;

__device__ __forceinline__ unsigned short f2b(float f) {
    union { float f; unsigned int u; } v; v.f = f;
    unsigned int u = v.u;
    u += 0x7fffu + ((u >> 16) & 1u);
    return (unsigned short)(u >> 16);
}
__device__ __forceinline__ float b2f(unsigned short h) {
    union { unsigned int u; float f; } v; v.u = ((unsigned int)h) << 16;
    return v.f;
}

// ---------------- K0: transpose X (2048x256) -> XT (256x2048) ----------------
__global__ __launch_bounds__(256) void k_transpose(const float* __restrict__ X,
                                                   float* __restrict__ XT) {
    int n = blockIdx.x, c = threadIdx.x;
    XT[c * NN + n] = X[n * 256 + c];
}

// ---------------- K1: per-node Ku = rbf(Zn,Zn) + jitter*I ----------------
__global__ __launch_bounds__(256) void k_ku(const float* __restrict__ Z,
                                            const int* __restrict__ pa,
                                            float* __restrict__ Kub) {
    __shared__ float Zs[128][33];
    __shared__ float zsq[128];
    __shared__ int cols[32];
    int node = blockIdx.x, t = threadIdx.x;
    if (t < 32) cols[t] = pa[node * 32 + t];
    __syncthreads();
    for (int i = t; i < 128 * 32; i += 256) {
        int m = i >> 5, j = i & 31;
        Zs[m][j] = Z[m * 256 + cols[j]];
    }
    __syncthreads();
    if (t < 128) {
        float s = 0.f;
        for (int j = 0; j < 32; j++) { float v = Zs[t][j]; s += v * v; }
        zsq[t] = s;
    }
    __syncthreads();
    int j = t & 127, ih = t >> 7;
    for (int ii = 0; ii < 64; ii++) {
        int i = ih * 64 + ii;
        float d = 0.f;
        #pragma unroll
        for (int p = 0; p < 32; p++) d += Zs[i][p] * Zs[j][p];
        float sq = zsq[i] + zsq[j] - 2.f * d;
        sq = fmaxf(sq, 0.f);
        float v = __expf(-0.5f * sq);
        if (i == j) v += JITTER;
        Kub[node * 16384 + i * 128 + j] = v;
    }
}

// ---------------- K2: register-resident AUGMENTED Gauss-Jordan inverse -------
// [A | B] with B init = I; after 128 steps B = A^{-1}. Each thread owns half a
// row of A (a[64]) and half a row of B (b[64]) in VGPRs -- ALL accesses use
// compile-time indices (rule #20). Pivot row broadcast via double-buffered LDS.
// The runtime-column read (ci = A[r][k]) is extracted during the PREVIOUS
// step's unrolled update via a wave-uniform scalar compare (j == kln).
// Pivot-row scaling is branchless: f_pivot = (1-piv)/piv gives A[k][:] /= piv.
__global__ __launch_bounds__(256, 1) void k_inv(const float* __restrict__ Kub,
                                                float* __restrict__ Kinvf,
                                                unsigned short* __restrict__ Hbuf) {
    __shared__ float pra[2][128];
    __shared__ float prb[2][128];
    int node = blockIdx.x, t = threadIdx.x;
    int r = t >> 1, h = t & 1;           // row, column-half (h*64 .. h*64+63)
    float a[64], b[64];
    const float* src = Kub + (size_t)node * 16384 + r * 128 + h * 64;
    #pragma unroll
    for (int j = 0; j < 64; j += 4) {
        f32x4 v = *(const f32x4*)(src + j);
        a[j] = v.x; a[j + 1] = v.y; a[j + 2] = v.z; a[j + 3] = v.w;
    }
    #pragma unroll
    for (int j = 0; j < 64; j++) b[j] = (h * 64 + j == r) ? 1.0f : 0.0f;

    // peel: ci for k=0 is A[r][0], held at a[0] by h==0 threads
    float cim = (h == 0) ? a[0] : 0.0f;

    #pragma unroll 1
    for (int k = 0; k < 128; ++k) {
        float* pa_ = pra[k & 1];
        float* pb_ = prb[k & 1];
        if (r == k) {
            #pragma unroll
            for (int j = 0; j < 64; j += 4) {
                f32x4 va; va.x = a[j]; va.y = a[j+1]; va.z = a[j+2]; va.w = a[j+3];
                f32x4 vb; vb.x = b[j]; vb.y = b[j+1]; vb.z = b[j+2]; vb.w = b[j+3];
                *(f32x4*)(pa_ + h * 64 + j) = va;
                *(f32x4*)(pb_ + h * 64 + j) = vb;
            }
        }
        __syncthreads();
        float piv = pa_[k];
        float ip = 1.0f / piv;
        float ci = cim + __shfl_xor(cim, 1);
        float f = (r == k) ? (1.0f - piv) * ip : -ci * ip;
        int kln = (k + 1) & 63, khn = (k + 1) >> 6;   // next step's column coords
        float cn = 0.0f;
        const f32x4* pa4 = (const f32x4*)(pa_ + h * 64);
        const f32x4* pb4 = (const f32x4*)(pb_ + h * 64);
        #pragma unroll
        for (int jc = 0; jc < 16; jc++) {
            f32x4 av = pa4[jc];
            f32x4 bv = pb4[jc];
            #pragma unroll
            for (int e = 0; e < 4; e++) {
                int j = jc * 4 + e;
                a[j] = fmaf(f, av[e], a[j]);
                b[j] = fmaf(f, bv[e], b[j]);
                if (j == kln) cn = a[j];   // wave-uniform scalar cond, static idx
            }
        }
        cim = (khn == h) ? cn : 0.0f;
        // double-buffered pivot rows: buffer k&1 is not rewritten until after
        // the k+1 barrier, by which point all threads finished reading it.
    }

    float* dstf = Kinvf + (size_t)node * 16384 + r * 128 + h * 64;
    unsigned short* dstb = Hbuf + (size_t)node * 81920 + (512 + r) * 128 + h * 64;
    #pragma unroll
    for (int j = 0; j < 64; j += 4) {
        f32x4 v; v.x = b[j]; v.y = b[j + 1]; v.z = b[j + 2]; v.w = b[j + 3];
        *(f32x4*)(dstf + j) = v;
        dstb[j] = f2b(b[j]); dstb[j + 1] = f2b(b[j + 1]);
        dstb[j + 2] = f2b(b[j + 2]); dstb[j + 3] = f2b(b[j + 3]);
    }
}

// ---------------- K3: W[d] = Kinv @ qmu_d ----------------
__global__ __launch_bounds__(256) void k_w(const float* __restrict__ Kinvf,
                                           const float* __restrict__ qmu,
                                           float* __restrict__ Wg) {
    int node = blockIdx.x, t = threadIdx.x;
    __shared__ float qs[512];  // [m][d]
    for (int i = t; i < 512; i += 256) qs[i] = qmu[(i >> 2) * 256 + node * 4 + (i & 3)];
    __syncthreads();
    for (int p = 0; p < 2; p++) {
        int o = t + p * 256;
        int d = o >> 7, i = o & 127;
        float s = 0.f;
        for (int j = 0; j < 128; j++)
            s += Kinvf[node * 16384 + i * 128 + j] * qs[j * 4 + d];
        Wg[node * 512 + d * 128 + i] = s;
    }
}

// ---------------- K4: Gt[d][m][j] = sum_p Lq[p][m] * Kinv[p][j]  (p>=m) ------
__global__ __launch_bounds__(256) void k_gt(const float* __restrict__ Kinvf,
                                            const float* __restrict__ qsqrt,
                                            unsigned short* __restrict__ Hbuf) {
    int nd = blockIdx.x;
    int node = nd >> 2, d = nd & 3;
    __shared__ float Lqs[32][132];
    __shared__ float Ks[32][132];
    int t = threadIdx.x;
    int tm = t & 15, tj = t >> 4;
    float acc[8][8] = {};
    const float* Lq = qsqrt + (size_t)nd * 16384;
    const float* Ki = Kinvf + (size_t)node * 16384;
    for (int pc = 0; pc < 128; pc += 32) {
        __syncthreads();
        for (int idx = t; idx < 32 * 128; idx += 256) {
            int pp = idx >> 7, m = idx & 127;
            int p = pc + pp;
            Lqs[pp][m] = (p >= m) ? Lq[p * 128 + m] : 0.f;
            Ks[pp][m] = Ki[p * 128 + m];
        }
        __syncthreads();
        for (int pp = 0; pp < 32; pp++) {
            float lv[8], kv[8];
            #pragma unroll
            for (int a = 0; a < 8; a++) lv[a] = Lqs[pp][tm * 8 + a];
            #pragma unroll
            for (int b = 0; b < 8; b++) kv[b] = Ks[pp][tj * 8 + b];
            #pragma unroll
            for (int a = 0; a < 8; a++)
                #pragma unroll
                for (int b = 0; b < 8; b++) acc[a][b] += lv[a] * kv[b];
        }
    }
    for (int a = 0; a < 8; a++)
        for (int b = 0; b < 8; b++)
            Hbuf[node * 81920 + (d * 128 + tm * 8 + a) * 128 + (tj * 8 + b)] = f2b(acc[a][b]);
}

// ---------------- K5: KufT[node][x][m] = rbf(Zn, Xn)  (bf16) ----------------
__global__ __launch_bounds__(256) void k_kuf(const float* __restrict__ Z,
                                             const float* __restrict__ XT,
                                             const int* __restrict__ pa,
                                             unsigned short* __restrict__ KufT) {
    int xt = blockIdx.x, node = blockIdx.y;
    __shared__ float Zs[128][33];
    __shared__ float Xs[32][132];
    __shared__ float zsq[128], xsq[128];
    __shared__ int cols[32];
    int t = threadIdx.x;
    if (t < 32) cols[t] = pa[node * 32 + t];
    __syncthreads();
    for (int i = t; i < 4096; i += 256) {
        int m = i >> 5, j = i & 31;
        Zs[m][j] = Z[m * 256 + cols[j]];
    }
    for (int i = t; i < 4096; i += 256) {
        int j = i >> 7, xl = i & 127;
        Xs[j][xl] = XT[cols[j] * NN + xt * 128 + xl];
    }
    __syncthreads();
    if (t < 128) {
        float s = 0.f;
        for (int j2 = 0; j2 < 32; j2++) { float v = Zs[t][j2]; s += v * v; }
        zsq[t] = s;
    } else {
        int x = t - 128;
        float s = 0.f;
        for (int j2 = 0; j2 < 32; j2++) { float v = Xs[j2][x]; s += v * v; }
        xsq[x] = s;
    }
    __syncthreads();
    int m = t & 127, xh = t >> 7;
    for (int xi = 0; xi < 64; xi++) {
        int xl = xh * 64 + xi;
        float dd = 0.f;
        #pragma unroll
        for (int p = 0; p < 32; p++) dd += Zs[m][p] * Xs[p][xl];
        float sq = zsq[m] + xsq[xl] - 2.f * dd;
        sq = fmaxf(sq, 0.f);
        KufT[(size_t)node * 262144 + (size_t)(xt * 128 + xl) * 128 + m] = f2b(__expf(-0.5f * sq));
    }
}

// ---------------- K6: main MFMA GEMM U = H @ Kuf + fused epilogue ------------
// grid (xt=16, rb=5, node=64), block 256 (4 waves, 2x2 wave tiling of 128x128)
__global__ __launch_bounds__(256) void k_main(const unsigned short* __restrict__ Hbuf,
                                              const unsigned short* __restrict__ KufT,
                                              const float* __restrict__ Wg,
                                              float* __restrict__ vsq,
                                              float* __restrict__ tb,
                                              float* __restrict__ meanb) {
    int xt = blockIdx.x, rb = blockIdx.y, node = blockIdx.z;
    __shared__ unsigned short S[32768];   // As = S[0..16384), Bs = S[16384..32768)
    unsigned short* As = S;
    unsigned short* Bs = S + 16384;
    int t = threadIdx.x;

    // stage A: H rows rb*128..+128 (seg-XOR swizzle within each 256B row)
    const unsigned short* Hg = Hbuf + (size_t)node * 81920 + (size_t)rb * 16384;
    #pragma unroll
    for (int i = 0; i < 8; i++) {
        int cid = t + i * 256;
        int r = cid >> 4, s = cid & 15;
        short8 v = *(const short8*)(Hg + r * 128 + s * 8);
        *(short8*)(As + r * 128 + ((s ^ (r & 7)) * 8)) = v;
    }
    // stage B: KufT rows xt*128..+128
    const unsigned short* Kg = KufT + (size_t)node * 262144 + (size_t)xt * 16384;
    #pragma unroll
    for (int i = 0; i < 8; i++) {
        int cid = t + i * 256;
        int r = cid >> 4, s = cid & 15;
        short8 v = *(const short8*)(Kg + r * 128 + s * 8);
        *(short8*)(Bs + r * 128 + ((s ^ (r & 7)) * 8)) = v;
    }
    __syncthreads();

    int wid = t >> 6, lane = t & 63;
    int wmI = wid & 1, wnI = wid >> 1;
    int wm = wmI * 64, wn = wnI * 64;
    int lr = lane & 15, lk = lane >> 4;

    f32x4 acc[4][4] = {};
    #pragma unroll
    for (int ks = 0; ks < 4; ks++) {
        int seg = ks * 4 + lk;
        short8 av[4], bv[4];
        #pragma unroll
        for (int mi = 0; mi < 4; mi++) {
            int r = wm + mi * 16 + lr;
            av[mi] = *(const short8*)(As + r * 128 + ((seg ^ (r & 7)) * 8));
        }
        #pragma unroll
        for (int ni = 0; ni < 4; ni++) {
            int x = wn + ni * 16 + lr;
            bv[ni] = *(const short8*)(Bs + x * 128 + ((seg ^ (x & 7)) * 8));
        }
        #pragma unroll
        for (int mi = 0; mi < 4; mi++)
            #pragma unroll
            for (int ni = 0; ni < 4; ni++)
                acc[mi][ni] = __builtin_amdgcn_mfma_f32_16x16x32_bf16(av[mi], bv[ni], acc[mi][ni], 0, 0, 0);
    }
    __syncthreads();

    float* dpart = (float*)S;   // overlays As (dead); Bs stays live
    if (rb < 4) {
        float sv[4];
        #pragma unroll
        for (int ni = 0; ni < 4; ni++) {
            float s = 0.f;
            #pragma unroll
            for (int mi = 0; mi < 4; mi++)
                #pragma unroll
                for (int j = 0; j < 4; j++) { float v = acc[mi][ni][j]; s += v * v; }
            s += __shfl_xor(s, 16);
            s += __shfl_xor(s, 32);
            sv[ni] = s;
        }
        if (lk == 0)
            #pragma unroll
            for (int ni = 0; ni < 4; ni++)
                dpart[wmI * 128 + wn + ni * 16 + lr] = sv[ni];
        __syncthreads();
        if (t < 128)
            vsq[node * 8192 + rb * 2048 + xt * 128 + t] = dpart[t] + dpart[128 + t];
    } else {
        // t-term: sum_i U[i][x] * k[i][x]
        float sv[4];
        #pragma unroll
        for (int ni = 0; ni < 4; ni++) {
            int x = wn + ni * 16 + lr;
            float s = 0.f;
            #pragma unroll
            for (int mi = 0; mi < 4; mi++)
                #pragma unroll
                for (int j = 0; j < 4; j++) {
                    int m = wm + mi * 16 + lk * 4 + j;
                    int seg = (m >> 3) ^ (x & 7);
                    float kv = b2f(Bs[x * 128 + seg * 8 + (m & 7)]);
                    s += acc[mi][ni][j] * kv;
                }
            s += __shfl_xor(s, 16);
            s += __shfl_xor(s, 32);
            sv[ni] = s;
        }
        if (lk == 0)
            #pragma unroll
            for (int ni = 0; ni < 4; ni++)
                dpart[wmI * 128 + wn + ni * 16 + lr] = sv[ni];
        __syncthreads();
        if (t < 128)
            tb[node * 2048 + xt * 128 + t] = dpart[t] + dpart[128 + t];
        // mean[d][x] = sum_m W[d][m] * k[m][x]
        for (int p = 0; p < 2; p++) {
            int o = t + p * 256;
            int d = o >> 7, xl = o & 127;
            float s = 0.f;
            for (int m2 = 0; m2 < 128; m2++) {
                int seg = (m2 >> 3) ^ (xl & 7);
                s += Wg[node * 512 + d * 128 + m2] * b2f(Bs[xl * 128 + seg * 8 + (m2 & 7)]);
            }
            meanb[node * 8192 + d * 2048 + xt * 128 + xl] = s;
        }
    }
}

// ---------------- K7: assemble outputs (LDS transpose for coalescing) --------
__global__ __launch_bounds__(256) void k_out(const float* __restrict__ meanb,
                                             const float* __restrict__ vsq,
                                             const float* __restrict__ tb,
                                             float* __restrict__ out) {
    __shared__ float mt[16][261];
    __shared__ float vt[16][261];
    int x0 = blockIdx.x * 16, t = threadIdx.x;
    int xl = t & 15, ch = t >> 4;
    for (int cc = 0; cc < 16; cc++) {
        int c = ch * 16 + cc;
        mt[xl][c] = meanb[c * 2048 + x0 + xl];
        vt[xl][c] = 1.0f + vsq[c * 2048 + x0 + xl] - tb[(c >> 2) * 2048 + x0 + xl];
    }
    __syncthreads();
    for (int xx = 0; xx < 16; xx++) {
        out[(x0 + xx) * 256 + t] = mt[xx][t];
        out[524288 + (x0 + xx) * 256 + t] = vt[xx][t];
    }
}

extern "C" void kernel_launch(void* const* d_in, const int* in_sizes, int n_in,
                              void* d_out, int out_size, void* d_ws, size_t ws_size,
                              hipStream_t stream) {
    const float* X = (const float*)d_in[0];
    const float* Z = (const float*)d_in[1];
    const float* qmu = (const float*)d_in[2];
    const float* qsqrt = (const float*)d_in[3];
    const int* pa = (const int*)d_in[4];
    float* out = (float*)d_out;

    char* ws = (char*)d_ws;
    size_t off = 0;
    float* XT = (float*)(ws + off);           off += 524288ull * 4;     // 2 MB
    float* Kub = (float*)(ws + off);          off += 1048576ull * 4;    // 4 MB
    float* Kinvf = (float*)(ws + off);        off += 1048576ull * 4;    // 4 MB
    float* Wg = (float*)(ws + off);           off += 32768ull * 4;      // 128 KB
    float* vsq = (float*)(ws + off);          off += 524288ull * 4;     // 2 MB
    float* tb = (float*)(ws + off);           off += 131072ull * 4;     // 512 KB
    float* meanb = (float*)(ws + off);        off += 524288ull * 4;     // 2 MB
    unsigned short* Hbuf = (unsigned short*)(ws + off);  off += 5242880ull * 2;   // 10 MB
    unsigned short* KufT = (unsigned short*)(ws + off);  off += 16777216ull * 2;  // 32 MB

    k_transpose<<<2048, 256, 0, stream>>>(X, XT);
    k_ku<<<64, 256, 0, stream>>>(Z, pa, Kub);
    k_inv<<<64, 256, 0, stream>>>(Kub, Kinvf, Hbuf);
    k_w<<<64, 256, 0, stream>>>(Kinvf, qmu, Wg);
    k_gt<<<256, 256, 0, stream>>>(Kinvf, qsqrt, Hbuf);
    k_kuf<<<dim3(16, 64), 256, 0, stream>>>(Z, XT, pa, KufT);
    k_main<<<dim3(16, 5, 64), 256, 0, stream>>>(Hbuf, KufT, Wg, vsq, tb, meanb);
    k_out<<<128, 256, 0, stream>>>(meanb, vsq, tb, out);
}